// Round 2
// baseline (574.482 us; speedup 1.0000x reference)
//
#include <hip/hip_runtime.h>
#include <cstddef>
#include <cstdint>

// Problem constants
#define K_CLS  19
#define C_DIM  256
#define HW     16384            // H*W = 128*128
#define B_DIM  8
#define NPIX   (B_DIM * HW)     // 131072 pixels
#define CHUNK  256              // pixels per block
#define NCHUNK (NPIX / CHUNK)   // 512 chunks
#define CH_PAD 20               // pad 19 -> 20 so class slots land in distinct banks
#define E_DIM  (C_DIM * K_CLS)  // 4864 (cls-sums per tensor)

// ws layout (floats):
//   [0, NCHUNK*2*E_DIM)                    partial sums, slice-major: slice ch -> [s:4864 | t:4864]
//   [P0, P0+2*E_DIM)   P0=NCHUNK*2*E_DIM   final sums (s then t), layout e = c*19 + cls
//   [P0+2*E_DIM, +19)                      class counts (atomic-accumulated -> must be zeroed)
// total ~19.96 MB

__global__ __launch_bounds__(256) void k_reduce(const float* __restrict__ fs,
                                                const float* __restrict__ ft,
                                                const int* __restrict__ lab,
                                                float* __restrict__ ws) {
    __shared__ float acc[C_DIM * CH_PAD];   // 20 KB, [c][cls] padded
    __shared__ float cnt[K_CLS];
    const int tid    = threadIdx.x;
    const int bid    = blockIdx.x;
    const int tensor = bid & 1;             // even: s, odd: t
    const int chunk  = bid >> 1;            // 0..511
    const int b      = chunk >> 6;          // 64 chunks per image
    const int p0     = (chunk & 63) << 8;   // *256 pixels

    for (int i = tid; i < C_DIM * CH_PAD; i += 256) acc[i] = 0.f;
    if (tid < K_CLS) cnt[tid] = 0.f;
    __syncthreads();

    const int lane = tid & 63, wave = tid >> 6;
    // each lane owns 4 fixed pixels for the whole block; labels live in registers
    const int4 lb = *reinterpret_cast<const int4*>(lab + b * HW + p0 + 4 * lane);
    if (tensor == 0 && wave == 0) {  // count each pixel exactly once (s-side, wave 0)
        atomicAdd(&cnt[lb.x], 1.f); atomicAdd(&cnt[lb.y], 1.f);
        atomicAdd(&cnt[lb.z], 1.f); atomicAdd(&cnt[lb.w], 1.f);
    }

    const float* base = (tensor ? ft : fs) + (size_t)b * C_DIM * HW + p0 + 4 * lane;
    // wave w handles channels {4*it + w}: within a wave all lanes share c, so the
    // 19 class slots (stride-1 in the padded [c][20] layout) hit 19 distinct banks.
    #pragma unroll 4
    for (int it = 0; it < 64; ++it) {
        const int c = it * 4 + wave;
        const float4 v = *reinterpret_cast<const float4*>(base + (size_t)c * HW);
        float* a = acc + c * CH_PAD;
        atomicAdd(a + lb.x, v.x); atomicAdd(a + lb.y, v.y);
        atomicAdd(a + lb.z, v.z); atomicAdd(a + lb.w, v.w);
    }
    __syncthreads();

    // private partial slice -> plain coalesced stores, no global atomics
    float* pslice = ws + (size_t)chunk * (2 * E_DIM) + tensor * E_DIM;
    for (int e = tid; e < E_DIM; e += 256) {
        const int c = e / K_CLS, k = e - c * K_CLS;
        pslice[e] = acc[c * CH_PAD + k];
    }
    if (tensor == 0 && tid < K_CLS)
        atomicAdd(ws + (size_t)NCHUNK * 2 * E_DIM + 2 * E_DIM + tid, cnt[tid]);
}

__global__ __launch_bounds__(256) void k_sum(float* __restrict__ ws) {
    const int e = blockIdx.x * 256 + threadIdx.x;
    if (e >= 2 * E_DIM) return;
    float a = 0.f;
    const float* p = ws + e;
    #pragma unroll 8
    for (int s = 0; s < NCHUNK; ++s) a += p[(size_t)s * 2 * E_DIM];
    ws[(size_t)NCHUNK * 2 * E_DIM + e] = a;
}

__global__ __launch_bounds__(256) void k_loss(const float* __restrict__ ws,
                                              float* __restrict__ out) {
    __shared__ float m[2][K_CLS][C_DIM + 1];   // normalized class means, 39 KB
    __shared__ float sim[2][K_CLS][K_CLS];
    __shared__ float cl[K_CLS];
    __shared__ float lrow[K_CLS];
    const int tid = threadIdx.x;
    const float* sums = ws + (size_t)NCHUNK * 2 * E_DIM;
    const float* cnts = sums + 2 * E_DIM;
    if (tid < K_CLS) cl[tid] = cnts[tid];
    __syncthreads();

    const int lane = tid & 63, wave = tid >> 6;
    // normalize(sums) == normalize(mean): the count*C division cancels; the eps
    // floor on ||mean|| maps to eps*count*C on ||sums||. count==0 -> zero row.
    for (int t2 = 0; t2 < 2; ++t2) {
        for (int r = wave; r < K_CLS; r += 4) {
            float v[4]; float ss = 0.f;
            #pragma unroll
            for (int i = 0; i < 4; ++i) {
                v[i] = sums[t2 * E_DIM + (4 * lane + i) * K_CLS + r];
                ss += v[i] * v[i];
            }
            #pragma unroll
            for (int msk = 1; msk < 64; msk <<= 1) ss += __shfl_xor(ss, msk);
            const float cv = cl[r];
            float scale = 0.f;
            if (cv > 0.f) {
                const float nrm = sqrtf(ss);
                scale = 1.f / fmaxf(nrm, 1e-12f * cv * (float)C_DIM);
            }
            #pragma unroll
            for (int i = 0; i < 4; ++i) m[t2][r][4 * lane + i] = v[i] * scale;
        }
    }
    __syncthreads();

    for (int p = tid; p < K_CLS * K_CLS; p += 256) {
        const int i = p / K_CLS, j = p - (p / K_CLS) * K_CLS;
        float as = 0.f, at = 0.f;
        for (int c = 0; c < C_DIM; ++c) {
            as += m[0][i][c] * m[0][j][c];
            at += m[1][i][c] * m[1][j][c];
        }
        sim[0][i][j] = as * 5.0f;   // 1/TEMP
        sim[1][i][j] = at * 5.0f;
    }
    __syncthreads();

    if (tid < K_CLS) {
        const int i = tid;
        float mxs = -1e30f, mxt = -1e30f;
        for (int j = 0; j < K_CLS; ++j) if (j != i) {
            mxs = fmaxf(mxs, sim[0][i][j]);
            mxt = fmaxf(mxt, sim[1][i][j]);
        }
        float es = 0.f, et = 0.f;
        for (int j = 0; j < K_CLS; ++j) if (j != i) {
            es += expf(sim[0][i][j] - mxs);
            et += expf(sim[1][i][j] - mxt);
        }
        const float ls = logf(es) + mxs, lt = logf(et) + mxt;
        float li = 0.f;
        for (int j = 0; j < K_CLS; ++j) if (j != i) {
            li += -expf(sim[1][i][j] - lt) * (sim[0][i][j] - ls);
        }
        lrow[i] = li;
    }
    __syncthreads();
    if (tid == 0) {
        float tot = 0.f;
        for (int i = 0; i < K_CLS; ++i) tot += lrow[i];
        out[0] = tot / (float)K_CLS;
    }
}

extern "C" void kernel_launch(void* const* d_in, const int* in_sizes, int n_in,
                              void* d_out, int out_size, void* d_ws, size_t ws_size,
                              hipStream_t stream) {
    const float* fs  = (const float*)d_in[0];
    const float* ft  = (const float*)d_in[1];
    const int*   lab = (const int*)d_in[2];
    float* ws = (float*)d_ws;
    // only the atomic-accumulated class-count region needs zeroing; partials and
    // final sums are fully overwritten every call (harness poisons ws with 0xAA)
    hipMemsetAsync(ws + (size_t)NCHUNK * 2 * E_DIM + 2 * E_DIM, 0,
                   K_CLS * sizeof(float), stream);
    k_reduce<<<NCHUNK * 2, 256, 0, stream>>>(fs, ft, lab, ws);
    k_sum<<<(2 * E_DIM + 255) / 256, 256, 0, stream>>>(ws);
    k_loss<<<1, 256, 0, stream>>>(ws, (float*)d_out);
}

// Round 8
// 394.864 us; speedup vs baseline: 1.4549x; 1.4549x over previous
//
#include <hip/hip_runtime.h>
#include <cstddef>
#include <cstdint>

#define K_CLS  19
#define C_DIM  256
#define HW     16384            // 128*128
#define NPIX   131072           // 8*HW
#define CHUNK_PIX 512           // pixels per k_reduce block
#define NCHUNK (NPIX / CHUNK_PIX)   // 256 chunks (x2 tensors = 512 blocks)
#define E_DIM  (C_DIM * K_CLS)      // 4864
#define LSTRIDE 65              // LDS pixel stride (64 + 1 pad -> conflict-free)

// ws layout (floats):
//   [0, NCHUNK*2*E_DIM)   partials: slice (chunk*2+tensor) -> [19][256] (k-major)
//   [P0, P0+2*E_DIM)      final sums, layout [t][k][c]
// ~10.0 MB total. No region needs pre-zeroing (all fully written before read).

__global__ __launch_bounds__(256) void k_reduce(const float* __restrict__ fs,
                                                const float* __restrict__ ft,
                                                const int* __restrict__ lab,
                                                float* __restrict__ ws) {
    __shared__ float tile[4][64 * LSTRIDE];   // per-wave [c_local][pixel], 66.5 KB
    const int tid  = threadIdx.x;
    const int lane = tid & 63, wave = tid >> 6;
    const int bid  = blockIdx.x;
    const int tensor = bid & 1;
    const int chunk  = bid >> 1;
    const int pixbase = chunk * CHUNK_PIX;
    const int b     = pixbase >> 14;          // / HW
    const int inpix = pixbase & (HW - 1);
    const int c0    = wave * 64;              // this wave's channel group
    const float* src = (tensor ? ft : fs) + ((size_t)b * C_DIM + c0) * HW + inpix;
    float* T = tile[wave];
    const int m = lane & 15, g = lane >> 4;

    float acc0=0.f, acc1=0.f, acc2=0.f, acc3=0.f, acc4=0.f, acc5=0.f, acc6=0.f,
          acc7=0.f, acc8=0.f, acc9=0.f, acc10=0.f, acc11=0.f, acc12=0.f,
          acc13=0.f, acc14=0.f, acc15=0.f, acc16=0.f, acc17=0.f, acc18=0.f;

    for (int s = 0; s < CHUNK_PIX / 64; ++s) {   // 8 subtiles of 64 pixels
        const int p0 = s * 64;
        // ---- stage 64ch x 64pix into LDS, transposed to [c][p] ----
        #pragma unroll
        for (int half = 0; half < 2; ++half) {
            float4 bufv[8];
            #pragma unroll
            for (int i = 0; i < 8; ++i) {
                const int c = (half * 8 + i) * 4 + g;      // 4 channels per instr
                bufv[i] = *reinterpret_cast<const float4*>(
                    src + (size_t)c * HW + p0 + 4 * m);    // 16 lanes = 256B contiguous
            }
            #pragma unroll
            for (int i = 0; i < 8; ++i) {
                const int c = (half * 8 + i) * 4 + g;
                float* d = T + c * LSTRIDE + 4 * m;        // banks (c+4m+i)%32: 2-way, free
                d[0] = bufv[i].x; d[1] = bufv[i].y; d[2] = bufv[i].z; d[3] = bufv[i].w;
            }
        }
        // labels for this subtile: lane (j>>2) holds pixels 4*(j>>2)+{0..3}
        const int4 li = *reinterpret_cast<const int4*>(lab + pixbase + p0 + 4 * m);

        // ---- accumulate: lane = channel, pixel index wave-uniform ----
        #pragma unroll
        for (int j = 0; j < 64; ++j) {
            const int comp = j & 3;                         // compile-time after unroll
            const int lv = comp == 0 ? li.x : comp == 1 ? li.y : comp == 2 ? li.z : li.w;
            const int k = __builtin_amdgcn_readlane(lv, j >> 2);  // uniform scalar label
            const float v = T[lane * LSTRIDE + j];          // bank (lane+j)%32: 2-way, free
            switch (k) {                                    // uniform 19-way scalar branch
                case 0:  acc0  += v; break;  case 1:  acc1  += v; break;
                case 2:  acc2  += v; break;  case 3:  acc3  += v; break;
                case 4:  acc4  += v; break;  case 5:  acc5  += v; break;
                case 6:  acc6  += v; break;  case 7:  acc7  += v; break;
                case 8:  acc8  += v; break;  case 9:  acc9  += v; break;
                case 10: acc10 += v; break;  case 11: acc11 += v; break;
                case 12: acc12 += v; break;  case 13: acc13 += v; break;
                case 14: acc14 += v; break;  case 15: acc15 += v; break;
                case 16: acc16 += v; break;  case 17: acc17 += v; break;
                default: acc18 += v; break;
            }
        }
    }
    // ---- write [19][256] partial slice, coalesced ----
    float* po = ws + (size_t)(chunk * 2 + tensor) * E_DIM + c0 + lane;
    po[0 * C_DIM]  = acc0;  po[1 * C_DIM]  = acc1;  po[2 * C_DIM]  = acc2;
    po[3 * C_DIM]  = acc3;  po[4 * C_DIM]  = acc4;  po[5 * C_DIM]  = acc5;
    po[6 * C_DIM]  = acc6;  po[7 * C_DIM]  = acc7;  po[8 * C_DIM]  = acc8;
    po[9 * C_DIM]  = acc9;  po[10 * C_DIM] = acc10; po[11 * C_DIM] = acc11;
    po[12 * C_DIM] = acc12; po[13 * C_DIM] = acc13; po[14 * C_DIM] = acc14;
    po[15 * C_DIM] = acc15; po[16 * C_DIM] = acc16; po[17 * C_DIM] = acc17;
    po[18 * C_DIM] = acc18;
}

__global__ __launch_bounds__(256) void k_sum(const float* __restrict__ ws,
                                             float* __restrict__ out) {
    const int e = blockIdx.x * 256 + threadIdx.x;   // 0..9727 over [t][k][c]
    if (e >= 2 * E_DIM) return;
    const int t = e / E_DIM, r = e - t * E_DIM;
    float a = 0.f;
    const float* p = ws + (size_t)t * E_DIM + r;
    #pragma unroll 8
    for (int ch = 0; ch < NCHUNK; ++ch)             // coalesced across threads
        a += p[(size_t)ch * 2 * E_DIM];
    out[e] = a;
}

__global__ __launch_bounds__(256) void k_loss(const float* __restrict__ sums,
                                              float* __restrict__ out) {
    __shared__ float mm[2][K_CLS][C_DIM + 1];  // normalized class means
    __shared__ float sim[2][K_CLS][K_CLS];
    __shared__ float lrow[K_CLS];
    const int tid = threadIdx.x;
    const int lane = tid & 63, wave = tid >> 6;

    // normalize(sums) == normalize(mean); the 1e-12 floor on ||mean|| maps to
    // 1e-12*cnt*C on ||sums|| (~1.8e-6) and can never bind for nonzero sums
    // (norm ~1e3); zero rows (empty class) -> scale 0, matching the reference.
    for (int t2 = 0; t2 < 2; ++t2) {
        for (int r = wave; r < K_CLS; r += 4) {
            const float4 v = *reinterpret_cast<const float4*>(
                sums + t2 * E_DIM + r * C_DIM + 4 * lane);
            float ss = v.x * v.x + v.y * v.y + v.z * v.z + v.w * v.w;
            #pragma unroll
            for (int msk = 1; msk < 64; msk <<= 1) ss += __shfl_xor(ss, msk);
            const float scale = (ss > 0.f) ? (1.f / sqrtf(ss)) : 0.f;
            mm[t2][r][4 * lane + 0] = v.x * scale;
            mm[t2][r][4 * lane + 1] = v.y * scale;
            mm[t2][r][4 * lane + 2] = v.z * scale;
            mm[t2][r][4 * lane + 3] = v.w * scale;
        }
    }
    __syncthreads();

    for (int p = tid; p < K_CLS * K_CLS; p += 256) {
        const int i = p / K_CLS, j = p - (p / K_CLS) * K_CLS;
        float as = 0.f, at = 0.f;
        for (int c = 0; c < C_DIM; ++c) {
            as += mm[0][i][c] * mm[0][j][c];
            at += mm[1][i][c] * mm[1][j][c];
        }
        sim[0][i][j] = as * 5.0f;   // 1/TEMP
        sim[1][i][j] = at * 5.0f;
    }
    __syncthreads();

    if (tid < K_CLS) {
        const int i = tid;
        float mxs = -1e30f, mxt = -1e30f;
        for (int j = 0; j < K_CLS; ++j) if (j != i) {
            mxs = fmaxf(mxs, sim[0][i][j]);
            mxt = fmaxf(mxt, sim[1][i][j]);
        }
        float es = 0.f, et = 0.f;
        for (int j = 0; j < K_CLS; ++j) if (j != i) {
            es += expf(sim[0][i][j] - mxs);
            et += expf(sim[1][i][j] - mxt);
        }
        const float ls = logf(es) + mxs, lt = logf(et) + mxt;
        float li = 0.f;
        for (int j = 0; j < K_CLS; ++j) if (j != i) {
            li += -expf(sim[1][i][j] - lt) * (sim[0][i][j] - ls);
        }
        lrow[i] = li;
    }
    __syncthreads();
    if (tid == 0) {
        float tot = 0.f;
        for (int i = 0; i < K_CLS; ++i) tot += lrow[i];
        out[0] = tot / (float)K_CLS;
    }
}

extern "C" void kernel_launch(void* const* d_in, const int* in_sizes, int n_in,
                              void* d_out, int out_size, void* d_ws, size_t ws_size,
                              hipStream_t stream) {
    const float* fs  = (const float*)d_in[0];
    const float* ft  = (const float*)d_in[1];
    const int*   lab = (const int*)d_in[2];
    float* ws = (float*)d_ws;
    float* finals = ws + (size_t)NCHUNK * 2 * E_DIM;

    k_reduce<<<NCHUNK * 2, 256, 0, stream>>>(fs, ft, lab, ws);
    k_sum<<<(2 * E_DIM + 255) / 256, 256, 0, stream>>>(ws, finals);
    k_loss<<<1, 256, 0, stream>>>(finals, (float*)d_out);
}